// Round 10
// baseline (133.469 us; speedup 1.0000x reference)
//
#include <hip/hip_runtime.h>
#include <hip/hip_bf16.h>

#define NHEADS 12
#define NFRAMES 8
#define NTOK 1568
#define CDIM 768
#define DHEAD 64
#define BATCH 2
#define MROWS (BATCH * NTOK) /* 3136 */
#define MPAD 3200
#define K3 (3 * CDIM)        /* 2304 */
#define AREA1 197
#define EXT1 228
#define TPF 196
#define LOG2E 1.4426950408889634f

typedef __bf16 bf16x8 __attribute__((ext_vector_type(8)));
typedef float f32x4 __attribute__((ext_vector_type(4)));
typedef float f32x16 __attribute__((ext_vector_type(16)));
typedef unsigned short u16x8 __attribute__((ext_vector_type(8)));

#if __has_builtin(__builtin_amdgcn_exp2f)
#define EXP2(x) __builtin_amdgcn_exp2f(x)
#else
#define EXP2(x) exp2f(x)
#endif

__device__ __forceinline__ unsigned short f2bf(float f) {
  return __builtin_bit_cast(unsigned short, (__bf16)f);
}
__device__ __forceinline__ float bf2f(unsigned short u) {
  unsigned int x = ((unsigned int)u) << 16;
  return __builtin_bit_cast(float, x);
}
__device__ __forceinline__ bf16x8 ld8(const unsigned short* p) {
  return __builtin_bit_cast(bf16x8, *(const u16x8*)p);
}
__device__ __forceinline__ f32x4 mfma16(bf16x8 a, bf16x8 b, f32x4 c) {
  return __builtin_amdgcn_mfma_f32_16x16x32_bf16(a, b, c, 0, 0, 0);
}
__device__ __forceinline__ f32x16 mfma32(bf16x8 a, bf16x8 b, f32x16 c) {
  return __builtin_amdgcn_mfma_f32_32x32x16_bf16(a, b, c, 0, 0, 0);
}
__device__ __forceinline__ unsigned int pack2(float lo, float hi) {
  return ((unsigned int)f2bf(hi) << 16) | (unsigned int)f2bf(lo);
}
// x = {a_lo, b_lo}, y = {a_hi, b_hi} across the lane<32 / lane>=32 halves.
__device__ __forceinline__ void swap32(unsigned int a, unsigned int b,
                                       unsigned int& x, unsigned int& y) {
#if __has_builtin(__builtin_amdgcn_permlane32_swap)
  auto r = __builtin_amdgcn_permlane32_swap(a, b, false, false);
  x = r[0]; y = r[1];
#else
  const bool hi = (threadIdx.x & 63) >= 32;
  unsigned int ea = (unsigned int)__shfl_xor((int)a, 32);
  unsigned int eb = (unsigned int)__shfl_xor((int)b, 32);
  x = hi ? eb : a;
  y = hi ? b : ea;
#endif
}

// ---------------- conversion / packing ----------------
__global__ void conv_kernel(const float* __restrict__ x,
                            const float* __restrict__ qkv_w,
                            const float* __restrict__ proj_w,
                            unsigned short* __restrict__ xb,
                            unsigned short* __restrict__ qkvwb,
                            unsigned short* __restrict__ projwb,
                            unsigned short* __restrict__ aout) {
  const int XCH = MPAD * CDIM / 4;
  const int WCH = K3 * CDIM / 4;
  const int PCH = CDIM * CDIM / 4;
  const int ACH = (MPAD - MROWS) * CDIM / 4;
  const int total = XCH + WCH + PCH + ACH;
  for (int c = blockIdx.x * blockDim.x + threadIdx.x; c < total;
       c += gridDim.x * blockDim.x) {
    if (c < XCH) {
      int m = (c * 4) / CDIM;
      float4 v = make_float4(0.f, 0.f, 0.f, 0.f);
      if (m < MROWS) v = ((const float4*)x)[c];
      ushort4 o;
      o.x = f2bf(v.x); o.y = f2bf(v.y); o.z = f2bf(v.z); o.w = f2bf(v.w);
      ((ushort4*)xb)[c] = o;
    } else if (c < XCH + WCH) {
      int c2 = c - XCH;
      float4 v = ((const float4*)qkv_w)[c2];
      ushort4 o;
      o.x = f2bf(v.x); o.y = f2bf(v.y); o.z = f2bf(v.z); o.w = f2bf(v.w);
      ((ushort4*)qkvwb)[c2] = o;
    } else if (c < XCH + WCH + PCH) {
      int c2 = c - XCH - WCH;
      float4 v = ((const float4*)proj_w)[c2];
      ushort4 o;
      o.x = f2bf(v.x); o.y = f2bf(v.y); o.z = f2bf(v.z); o.w = f2bf(v.w);
      ((ushort4*)projwb)[c2] = o;
    } else {
      int c2 = c - XCH - WCH - PCH;
      ushort4 z; z.x = 0; z.y = 0; z.z = 0; z.w = 0;
      ((ushort4*)(aout + (size_t)MROWS * CDIM))[c2] = z;
    }
  }
}

// ---------------- bias table pre-gather ----------------
// bias1Q[h][i=qmod<197][j=km_ext<228] (bf16, pre-scaled by log2e).
// bias2[h][qframe][kframe] (f32, xlog2e).
__global__ void bias_kernel(const float* __restrict__ rpt,
                            const float* __restrict__ rtt,
                            const int* __restrict__ rpi,
                            const int* __restrict__ rti,
                            unsigned short* __restrict__ bias1Q,
                            float* __restrict__ bias2) {
  int t = blockIdx.x * blockDim.x + threadIdx.x;
  const int n1 = NHEADS * AREA1 * EXT1;
  if (t < n1) {
    int h = t / (AREA1 * EXT1);
    int rem = t - h * (AREA1 * EXT1);
    int i = rem / EXT1;                 // qmod
    int j = rem - i * EXT1;             // km extended
    int jm = (j >= AREA1) ? j - AREA1 : j;
    bias1Q[t] = f2bf(rpt[rpi[i * AREA1 + jm] * NHEADS + h] * LOG2E);
  } else if (t < n1 + NHEADS * 64) {
    int t2 = t - n1;
    int h = t2 >> 6, ff = t2 & 63;
    bias2[t2] = rtt[rti[ff] * NHEADS + h] * LOG2E;
  }
}

// ---------------- BM x BN MFMA GEMM (NT: both A,B row-major over K) ----------------
template <int MODE, int BM, int BN>
__global__ __launch_bounds__(256) void gemm_kernel(
    const unsigned short* __restrict__ A,
    const unsigned short* __restrict__ Bw,
    const float* __restrict__ bias0,   // q_bias (MODE0) / proj_b (MODE1)
    const float* __restrict__ biasv,   // v_bias (MODE0)
    unsigned short* __restrict__ qbuf,
    unsigned short* __restrict__ kbuf,
    unsigned short* __restrict__ vtbuf,
    float* __restrict__ Cout) {
  __shared__ unsigned short As[2][BM * 32];
  __shared__ unsigned short Bs[2][BN * 32];
  const int lane = threadIdx.x & 63;
  const int wv = threadIdx.x >> 6;
  const int tid = threadIdx.x;
  const int m0 = blockIdx.y * BM;
  const int n0 = blockIdx.x * BN;
  constexpr int WM = BM / 2, WN = BN / 2;

  auto stage = [&](int buf, int kt) {
    const int k0 = kt * 32;
#pragma unroll
    for (int ai = 0; ai < BM / 64; ++ai) {
      const int c = ai * 256 + tid;
      const int r = c >> 2, seg = c & 3;
      __builtin_amdgcn_global_load_lds(
          (const __attribute__((address_space(1))) void*)(A + (size_t)(m0 + r) * CDIM + k0 + seg * 8),
          (__attribute__((address_space(3))) void*)&As[buf][c * 8], 16, 0, 0);
    }
#pragma unroll
    for (int bi = 0; bi < BN / 64; ++bi) {
      const int c = bi * 256 + tid;
      const int r = c >> 2, seg = c & 3;
      __builtin_amdgcn_global_load_lds(
          (const __attribute__((address_space(1))) void*)(Bw + (size_t)(n0 + r) * CDIM + k0 + seg * 8),
          (__attribute__((address_space(3))) void*)&Bs[buf][c * 8], 16, 0, 0);
    }
  };

  f32x4 acc[WM / 16][WN / 16] = {};
  const int rbase = (wv >> 1) * WM;
  const int cbase = (wv & 1) * WN;

  stage(0, 0);
  __syncthreads();
  int cur = 0;
  for (int kt = 0; kt < CDIM / 32; ++kt) {
    if (kt + 1 < CDIM / 32) stage(cur ^ 1, kt + 1);
    bf16x8 af[WM / 16], bg[WN / 16];
#pragma unroll
    for (int i = 0; i < WM / 16; ++i)
      af[i] = ld8(&As[cur][(rbase + i * 16 + (lane & 15)) * 32 + (lane >> 4) * 8]);
#pragma unroll
    for (int j = 0; j < WN / 16; ++j)
      bg[j] = ld8(&Bs[cur][(cbase + j * 16 + (lane & 15)) * 32 + (lane >> 4) * 8]);
#pragma unroll
    for (int i = 0; i < WM / 16; ++i)
#pragma unroll
      for (int j = 0; j < WN / 16; ++j)
        acc[i][j] = mfma16(af[i], bg[j], acc[i][j]);
    __syncthreads();
    cur ^= 1;
  }

#pragma unroll
  for (int i = 0; i < WM / 16; ++i) {
#pragma unroll
    for (int j = 0; j < WN / 16; ++j) {
#pragma unroll
      for (int r = 0; r < 4; ++r) {
        int grow = m0 + rbase + i * 16 + (lane >> 4) * 4 + r;
        int gcol = n0 + cbase + j * 16 + (lane & 15);
        if (grow >= MROWS) continue;
        float v = acc[i][j][r];
        if (MODE == 0) {
          int which = gcol / CDIM;
          int cc = gcol - which * CDIM;
          int hh = cc >> 6, dd = cc & 63;
          int b = grow / NTOK, n = grow - b * NTOK;
          size_t hd = ((size_t)(b * NHEADS + hh) * NTOK + n) * 64 + dd;
          if (which == 0)
            qbuf[hd] = f2bf((v + bias0[cc]) * (0.125f * LOG2E));  // exp2-domain fold
          else if (which == 1)
            kbuf[hd] = f2bf(v);
          else
            vtbuf[((size_t)(b * NHEADS + hh) * 64 + dd) * NTOK + n] =
                f2bf(v + biasv[cc]);
        } else {
          Cout[(size_t)grow * CDIM + gcol] = v + bias0[gcol];
        }
      }
    }
  }
}

// ---------------- flash attention v10: q-split + LDS-staged KV (T3 2-phase) --------
// 312 blocks = 24 bh x 13; block's 4 waves own q-tiles blk*4+wv (different q, SAME
// k-tile stream). Per k-tile: 8 global_load_lds (1KB each; 1 K-inst + 1 V-inst per
// wave) into double-buffered LDS (16KB), one __syncthreads (vmcnt drain paces DMA).
// K LDS XOR-swizzled: slot=(c*2+hi)^(row&7), staged via pre-swizzled SOURCE (rule
// #21) -> bank-even reads. V [64][32]: 2-way aliasing = free. No cross-wave merge.
// R9 lesson: compiler sinks register prefetch (VGPR stayed 100 w/ (256,2) bound);
// global_load_lds is the only source-level way to keep loads in flight.
__global__ __launch_bounds__(256) void attn_kernel(
    const unsigned short* __restrict__ qbuf,
    const unsigned short* __restrict__ kbuf,
    const unsigned short* __restrict__ vtbuf,
    const unsigned short* __restrict__ bias1Q,
    const float* __restrict__ bias2,
    unsigned short* __restrict__ aout) {
  __shared__ unsigned short Ks[2][2048];  // 32 rows x 64, XOR-swizzled, 4KB/buf
  __shared__ unsigned short Vs[2][2048];  // 64 rows x 32, linear, 4KB/buf
  const int lane = threadIdx.x & 63;
  const int wv = threadIdx.x >> 6;
  const int wu = (blockIdx.x & 7) * 39 + (blockIdx.x >> 3);  // bijective, 312=8*39
  const int bh = wu / 13;
  const int blk = wu - bh * 13;
  const int qt = blk * 4 + wv;             // 0..51; 49..51 inactive
  const bool active = qt < 49;
  const int q0 = active ? qt * 32 : 0;
  const int h = bh % NHEADS;
  const int b = bh / NHEADS;
  const int qlane = lane & 31;
  const int hi = lane >> 5;
  const int hi4 = hi * 4;
  const int qn = q0 + qlane;
  const int qfr = qn / TPF < 7 ? qn / TPF : 7;
  const int qmod = qn % AREA1;

  const unsigned short* qp = qbuf + (size_t)bh * NTOK * DHEAD;
  const unsigned short* kp = kbuf + (size_t)bh * NTOK * DHEAD;
  const unsigned short* vp = vtbuf + (size_t)bh * DHEAD * NTOK;
  const unsigned short* bq = bias1Q + ((size_t)h * AREA1 + qmod) * EXT1 + hi4;
  const float* b2q = bias2 + h * 64 + qfr * 8;

  // per-lane staging source indices (pre-swizzled for K)
  const int krow = lane >> 3;                       // 0..7
  const int kcol = ((lane & 7) ^ krow) * 8;         // swizzled 16B chunk (elems)
  const unsigned short* kstage = kp + (size_t)(wv * 8 + krow) * DHEAD + kcol;
  const int vrow = wv * 16 + (lane >> 2);           // 0..63 (d index)
  const int vcol = (lane & 3) * 8;                  // elems within 32-col slice
  const unsigned short* vstage = vp + (size_t)vrow * NTOK + vcol;

  auto stage = [&](int buf, int kv0) {
    __builtin_amdgcn_global_load_lds(
        (const __attribute__((address_space(1))) void*)(kstage + (size_t)kv0 * DHEAD),
        (__attribute__((address_space(3))) void*)&Ks[buf][wv * 512], 16, 0, 0);
    __builtin_amdgcn_global_load_lds(
        (const __attribute__((address_space(1))) void*)(vstage + kv0),
        (__attribute__((address_space(3))) void*)&Vs[buf][wv * 512], 16, 0, 0);
  };

  bf16x8 aq[4];
#pragma unroll
  for (int c = 0; c < 4; ++c)
    aq[c] = ld8(qp + (size_t)qn * DHEAD + c * 16 + hi * 8);

  f32x16 o0 = {}, o1 = {};
  float mrun = -1.0e30f, lrun = 0.f;

  stage(0, 0);
  unsigned short ub[16];
  {
    const unsigned short* bp = bq;  // base = 0
#pragma unroll
    for (int r = 0; r < 16; ++r) ub[r] = bp[(r & 3) + 8 * (r >> 2)];
  }
  float b2lo = b2q[0], b2hi = b2q[1];
  int base = 0, ccr = TPF, kfl = 0;
  __syncthreads();

  int cur = 0;
  for (int t = 0; t < NTOK / 32; ++t) {
    const int kv0 = t * 32;
    if (t + 1 < NTOK / 32) stage(cur ^ 1, kv0 + 32);

    // K fragments from swizzled LDS; V fragments from linear LDS
    bf16x8 kf[4], vf[4];
#pragma unroll
    for (int c = 0; c < 4; ++c)
      kf[c] = ld8(&Ks[cur][qlane * 64 + ((((c << 1) + hi) ^ (qlane & 7)) << 3)]);
    vf[0] = ld8(&Vs[cur][qlane * 32 + hi * 8]);
    vf[1] = ld8(&Vs[cur][qlane * 32 + 16 + hi * 8]);
    vf[2] = ld8(&Vs[cur][(32 + qlane) * 32 + hi * 8]);
    vf[3] = ld8(&Vs[cur][(32 + qlane) * 32 + 16 + hi * 8]);

    f32x16 s;
#pragma unroll
    for (int r = 0; r < 16; ++r) s[r] = bf2f(ub[r]);
    __builtin_amdgcn_s_setprio(1);
#pragma unroll
    for (int c = 0; c < 4; ++c) s = mfma32(kf[c], aq[c], s);
    __builtin_amdgcn_s_setprio(0);

    // prefetch next tile's bias1 chunk (completes by the barrier's vmcnt drain)
    int basen = base + 32; if (basen >= AREA1) basen -= AREA1;
    if (t + 1 < NTOK / 32) {
      const unsigned short* bp = bq + basen;
#pragma unroll
      for (int r = 0; r < 16; ++r) ub[r] = bp[(r & 3) + 8 * (r >> 2)];
    }

    // bias2: uniform per tile unless crossing a frame boundary (ccr < 32)
    if (ccr < 32) {
      const float dlt = b2hi - b2lo;
#pragma unroll
      for (int r = 0; r < 16; ++r)
        s[r] += ((r & 3) + 8 * (r >> 2) + hi4 >= ccr) ? dlt : 0.f;
    }

    // max tree + cross-half via permlane
    float a0 = fmaxf(fmaxf(s[0], s[1]), s[2]);
    float a1 = fmaxf(fmaxf(s[3], s[4]), s[5]);
    float a2 = fmaxf(fmaxf(s[6], s[7]), s[8]);
    float a3 = fmaxf(fmaxf(s[9], s[10]), s[11]);
    float a4 = fmaxf(fmaxf(s[12], s[13]), s[14]);
    float tmax = fmaxf(fmaxf(fmaxf(a0, a1), a2), fmaxf(fmaxf(a3, a4), s[15]));
    {
      unsigned int tx, ty;
      swap32(__builtin_bit_cast(unsigned int, tmax),
             __builtin_bit_cast(unsigned int, tmax), tx, ty);
      tmax = fmaxf(__builtin_bit_cast(float, tx), __builtin_bit_cast(float, ty));
    }
    const float tb = tmax + b2lo;
    if (!__all(tb - mrun <= 11.5f)) {  // T13 defer-max (log2 domain)
      const float mnew = fmaxf(mrun, tb);
      const float fac = EXP2(mrun - mnew);
      lrun *= fac;
#pragma unroll
      for (int r = 0; r < 16; ++r) { o0[r] *= fac; o1[r] *= fac; }
      mrun = mnew;
    }
    const float mm = mrun - b2lo;
#pragma unroll
    for (int r = 0; r < 16; ++r) s[r] = EXP2(s[r] - mm);
    float s0a = (s[0] + s[1]) + (s[2] + s[3]);
    float s1a = (s[4] + s[5]) + (s[6] + s[7]);
    float s2a = (s[8] + s[9]) + (s[10] + s[11]);
    float s3a = (s[12] + s[13]) + (s[14] + s[15]);
    float ps = (s0a + s1a) + (s2a + s3a);
    {
      unsigned int px, py;
      swap32(__builtin_bit_cast(unsigned int, ps),
             __builtin_bit_cast(unsigned int, ps), px, py);
      ps = __builtin_bit_cast(float, px) + __builtin_bit_cast(float, py);
    }
    lrun += ps;

    // pack P -> bf16 pairs; exchange halves via permlane32_swap
    unsigned int dw[8];
#pragma unroll
    for (int c = 0; c < 8; ++c) dw[c] = pack2(s[2 * c], s[2 * c + 1]);
    unsigned int f0[4], f1[4];
    swap32(dw[0], dw[2], f0[0], f0[2]);
    swap32(dw[1], dw[3], f0[1], f0[3]);
    swap32(dw[4], dw[6], f1[0], f1[2]);
    swap32(dw[5], dw[7], f1[1], f1[3]);
    const bf16x8 F0 = __builtin_bit_cast(bf16x8, *(ulonglong2*)f0);
    const bf16x8 F1 = __builtin_bit_cast(bf16x8, *(ulonglong2*)f1);

    __builtin_amdgcn_s_setprio(1);
    o0 = mfma32(vf[0], F0, o0);
    o0 = mfma32(vf[1], F1, o0);
    o1 = mfma32(vf[2], F0, o1);
    o1 = mfma32(vf[3], F1, o1);
    __builtin_amdgcn_s_setprio(0);

    __syncthreads();
    cur ^= 1;
    base = basen;
    ccr -= 32;
    if (ccr <= 0) {
      kfl++;
      ccr += TPF;
      b2lo = b2q[kfl];
      b2hi = b2q[kfl < 7 ? kfl + 1 : 7];
    }
  }

  if (active) {
    const float rinv = 1.0f / lrun;
    unsigned short* op = aout + (size_t)(b * NTOK + qn) * CDIM + h * 64;
#pragma unroll
    for (int c = 0; c < 8; ++c) {
      const int d0 = 8 * (c >> 1) + 4 * hi + 2 * (c & 1);
      *(unsigned int*)(op + d0) = pack2(o0[2 * c] * rinv, o0[2 * c + 1] * rinv);
      *(unsigned int*)(op + 32 + d0) = pack2(o1[2 * c] * rinv, o1[2 * c + 1] * rinv);
    }
  }
}

extern "C" void kernel_launch(void* const* d_in, const int* in_sizes, int n_in,
                              void* d_out, int out_size, void* d_ws, size_t ws_size,
                              hipStream_t stream) {
  (void)in_sizes; (void)n_in; (void)out_size; (void)ws_size;
  const float* x        = (const float*)d_in[0];
  const float* qkv_w    = (const float*)d_in[1];
  const float* q_bias   = (const float*)d_in[2];
  const float* v_bias   = (const float*)d_in[3];
  const float* rp_table = (const float*)d_in[4];
  const float* rt_table = (const float*)d_in[5];
  const float* proj_w   = (const float*)d_in[6];
  const float* proj_b   = (const float*)d_in[7];
  const int* rp_index   = (const int*)d_in[8];
  const int* rt_index   = (const int*)d_in[9];

  char* ws = (char*)d_ws;
  unsigned short* xb     = (unsigned short*)(ws);
  unsigned short* qkvwb  = (unsigned short*)(ws + 4915200);
  unsigned short* projwb = (unsigned short*)(ws + 8454144);
  unsigned short* qbuf   = (unsigned short*)(ws + 9633792);
  unsigned short* kbuf   = (unsigned short*)(ws + 14450688);
  unsigned short* vtbuf  = (unsigned short*)(ws + 19267584);
  unsigned short* aout   = (unsigned short*)(ws + 24084480);
  unsigned short* bias1Q = (unsigned short*)(ws + 28999680);  // 12*197*228*2 B
  float* bias2           = (float*)(ws + 30247424);

  conv_kernel<<<2048, 256, 0, stream>>>(x, qkv_w, proj_w, xb, qkvwb, projwb, aout);
  bias_kernel<<<(NHEADS * AREA1 * EXT1 + NHEADS * 64 + 255) / 256, 256, 0, stream>>>(
      rp_table, rt_table, rp_index, rt_index, bias1Q, bias2);
  gemm_kernel<0, 128, 64><<<dim3(K3 / 64, MPAD / 128), 256, 0, stream>>>(
      xb, qkvwb, q_bias, v_bias, qbuf, kbuf, vtbuf, nullptr);
  attn_kernel<<<dim3(312), 256, 0, stream>>>(
      qbuf, kbuf, vtbuf, bias1Q, bias2, aout);
  gemm_kernel<1, 64, 64><<<dim3(CDIM / 64, MPAD / 64), 256, 0, stream>>>(
      aout, projwb, proj_b, nullptr, nullptr, nullptr, nullptr, (float*)d_out);
}

// Round 11
// 128.703 us; speedup vs baseline: 1.0370x; 1.0370x over previous
//
#include <hip/hip_runtime.h>
#include <hip/hip_bf16.h>

#define NHEADS 12
#define NFRAMES 8
#define NTOK 1568
#define CDIM 768
#define DHEAD 64
#define BATCH 2
#define MROWS (BATCH * NTOK) /* 3136 */
#define MPAD 3200
#define K3 (3 * CDIM)        /* 2304 */
#define AREA1 197
#define EXT1 228
#define TPF 196
#define LOG2E 1.4426950408889634f

typedef __bf16 bf16x8 __attribute__((ext_vector_type(8)));
typedef float f32x4 __attribute__((ext_vector_type(4)));
typedef float f32x16 __attribute__((ext_vector_type(16)));
typedef unsigned short u16x8 __attribute__((ext_vector_type(8)));

#if __has_builtin(__builtin_amdgcn_exp2f)
#define EXP2(x) __builtin_amdgcn_exp2f(x)
#else
#define EXP2(x) exp2f(x)
#endif

__device__ __forceinline__ unsigned short f2bf(float f) {
  return __builtin_bit_cast(unsigned short, (__bf16)f);
}
__device__ __forceinline__ float bf2f(unsigned short u) {
  unsigned int x = ((unsigned int)u) << 16;
  return __builtin_bit_cast(float, x);
}
__device__ __forceinline__ bf16x8 ld8(const unsigned short* p) {
  return __builtin_bit_cast(bf16x8, *(const u16x8*)p);
}
__device__ __forceinline__ f32x4 mfma16(bf16x8 a, bf16x8 b, f32x4 c) {
  return __builtin_amdgcn_mfma_f32_16x16x32_bf16(a, b, c, 0, 0, 0);
}
__device__ __forceinline__ f32x16 mfma32(bf16x8 a, bf16x8 b, f32x16 c) {
  return __builtin_amdgcn_mfma_f32_32x32x16_bf16(a, b, c, 0, 0, 0);
}
__device__ __forceinline__ unsigned int pack2(float lo, float hi) {
  return ((unsigned int)f2bf(hi) << 16) | (unsigned int)f2bf(lo);
}
// x = {a_lo, b_lo}, y = {a_hi, b_hi} across the lane<32 / lane>=32 halves.
__device__ __forceinline__ void swap32(unsigned int a, unsigned int b,
                                       unsigned int& x, unsigned int& y) {
#if __has_builtin(__builtin_amdgcn_permlane32_swap)
  auto r = __builtin_amdgcn_permlane32_swap(a, b, false, false);
  x = r[0]; y = r[1];
#else
  const bool hi = (threadIdx.x & 63) >= 32;
  unsigned int ea = (unsigned int)__shfl_xor((int)a, 32);
  unsigned int eb = (unsigned int)__shfl_xor((int)b, 32);
  x = hi ? eb : a;
  y = hi ? b : ea;
#endif
}

// ---------------- conversion / packing ----------------
__global__ void conv_kernel(const float* __restrict__ x,
                            const float* __restrict__ qkv_w,
                            const float* __restrict__ proj_w,
                            unsigned short* __restrict__ xb,
                            unsigned short* __restrict__ qkvwb,
                            unsigned short* __restrict__ projwb,
                            unsigned short* __restrict__ aout) {
  const int XCH = MPAD * CDIM / 4;
  const int WCH = K3 * CDIM / 4;
  const int PCH = CDIM * CDIM / 4;
  const int ACH = (MPAD - MROWS) * CDIM / 4;
  const int total = XCH + WCH + PCH + ACH;
  for (int c = blockIdx.x * blockDim.x + threadIdx.x; c < total;
       c += gridDim.x * blockDim.x) {
    if (c < XCH) {
      int m = (c * 4) / CDIM;
      float4 v = make_float4(0.f, 0.f, 0.f, 0.f);
      if (m < MROWS) v = ((const float4*)x)[c];
      ushort4 o;
      o.x = f2bf(v.x); o.y = f2bf(v.y); o.z = f2bf(v.z); o.w = f2bf(v.w);
      ((ushort4*)xb)[c] = o;
    } else if (c < XCH + WCH) {
      int c2 = c - XCH;
      float4 v = ((const float4*)qkv_w)[c2];
      ushort4 o;
      o.x = f2bf(v.x); o.y = f2bf(v.y); o.z = f2bf(v.z); o.w = f2bf(v.w);
      ((ushort4*)qkvwb)[c2] = o;
    } else if (c < XCH + WCH + PCH) {
      int c2 = c - XCH - WCH;
      float4 v = ((const float4*)proj_w)[c2];
      ushort4 o;
      o.x = f2bf(v.x); o.y = f2bf(v.y); o.z = f2bf(v.z); o.w = f2bf(v.w);
      ((ushort4*)projwb)[c2] = o;
    } else {
      int c2 = c - XCH - WCH - PCH;
      ushort4 z; z.x = 0; z.y = 0; z.z = 0; z.w = 0;
      ((ushort4*)(aout + (size_t)MROWS * CDIM))[c2] = z;
    }
  }
}

// ---------------- bias table pre-gather ----------------
// bias1Q[h][i=qmod<197][j=km_ext<228] (bf16, pre-scaled by log2e).
// bias2[h][qframe][kframe] (f32, xlog2e).
__global__ void bias_kernel(const float* __restrict__ rpt,
                            const float* __restrict__ rtt,
                            const int* __restrict__ rpi,
                            const int* __restrict__ rti,
                            unsigned short* __restrict__ bias1Q,
                            float* __restrict__ bias2) {
  int t = blockIdx.x * blockDim.x + threadIdx.x;
  const int n1 = NHEADS * AREA1 * EXT1;
  if (t < n1) {
    int h = t / (AREA1 * EXT1);
    int rem = t - h * (AREA1 * EXT1);
    int i = rem / EXT1;                 // qmod
    int j = rem - i * EXT1;             // km extended
    int jm = (j >= AREA1) ? j - AREA1 : j;
    bias1Q[t] = f2bf(rpt[rpi[i * AREA1 + jm] * NHEADS + h] * LOG2E);
  } else if (t < n1 + NHEADS * 64) {
    int t2 = t - n1;
    int h = t2 >> 6, ff = t2 & 63;
    bias2[t2] = rtt[rti[ff] * NHEADS + h] * LOG2E;
  }
}

// ---------------- BM x BN MFMA GEMM (NT: both A,B row-major over K) ----------------
template <int MODE, int BM, int BN>
__global__ __launch_bounds__(256) void gemm_kernel(
    const unsigned short* __restrict__ A,
    const unsigned short* __restrict__ Bw,
    const float* __restrict__ bias0,   // q_bias (MODE0) / proj_b (MODE1)
    const float* __restrict__ biasv,   // v_bias (MODE0)
    unsigned short* __restrict__ qbuf,
    unsigned short* __restrict__ kbuf,
    unsigned short* __restrict__ vtbuf,
    float* __restrict__ Cout) {
  __shared__ unsigned short As[2][BM * 32];
  __shared__ unsigned short Bs[2][BN * 32];
  const int lane = threadIdx.x & 63;
  const int wv = threadIdx.x >> 6;
  const int tid = threadIdx.x;
  const int m0 = blockIdx.y * BM;
  const int n0 = blockIdx.x * BN;
  constexpr int WM = BM / 2, WN = BN / 2;

  auto stage = [&](int buf, int kt) {
    const int k0 = kt * 32;
#pragma unroll
    for (int ai = 0; ai < BM / 64; ++ai) {
      const int c = ai * 256 + tid;
      const int r = c >> 2, seg = c & 3;
      __builtin_amdgcn_global_load_lds(
          (const __attribute__((address_space(1))) void*)(A + (size_t)(m0 + r) * CDIM + k0 + seg * 8),
          (__attribute__((address_space(3))) void*)&As[buf][c * 8], 16, 0, 0);
    }
#pragma unroll
    for (int bi = 0; bi < BN / 64; ++bi) {
      const int c = bi * 256 + tid;
      const int r = c >> 2, seg = c & 3;
      __builtin_amdgcn_global_load_lds(
          (const __attribute__((address_space(1))) void*)(Bw + (size_t)(n0 + r) * CDIM + k0 + seg * 8),
          (__attribute__((address_space(3))) void*)&Bs[buf][c * 8], 16, 0, 0);
    }
  };

  f32x4 acc[WM / 16][WN / 16] = {};
  const int rbase = (wv >> 1) * WM;
  const int cbase = (wv & 1) * WN;

  stage(0, 0);
  __syncthreads();
  int cur = 0;
  for (int kt = 0; kt < CDIM / 32; ++kt) {
    if (kt + 1 < CDIM / 32) stage(cur ^ 1, kt + 1);
    bf16x8 af[WM / 16], bg[WN / 16];
#pragma unroll
    for (int i = 0; i < WM / 16; ++i)
      af[i] = ld8(&As[cur][(rbase + i * 16 + (lane & 15)) * 32 + (lane >> 4) * 8]);
#pragma unroll
    for (int j = 0; j < WN / 16; ++j)
      bg[j] = ld8(&Bs[cur][(cbase + j * 16 + (lane & 15)) * 32 + (lane >> 4) * 8]);
#pragma unroll
    for (int i = 0; i < WM / 16; ++i)
#pragma unroll
      for (int j = 0; j < WN / 16; ++j)
        acc[i][j] = mfma16(af[i], bg[j], acc[i][j]);
    __syncthreads();
    cur ^= 1;
  }

#pragma unroll
  for (int i = 0; i < WM / 16; ++i) {
#pragma unroll
    for (int j = 0; j < WN / 16; ++j) {
#pragma unroll
      for (int r = 0; r < 4; ++r) {
        int grow = m0 + rbase + i * 16 + (lane >> 4) * 4 + r;
        int gcol = n0 + cbase + j * 16 + (lane & 15);
        if (grow >= MROWS) continue;
        float v = acc[i][j][r];
        if (MODE == 0) {
          int which = gcol / CDIM;
          int cc = gcol - which * CDIM;
          int hh = cc >> 6, dd = cc & 63;
          int b = grow / NTOK, n = grow - b * NTOK;
          size_t hd = ((size_t)(b * NHEADS + hh) * NTOK + n) * 64 + dd;
          if (which == 0)
            qbuf[hd] = f2bf((v + bias0[cc]) * (0.125f * LOG2E));  // exp2-domain fold
          else if (which == 1)
            kbuf[hd] = f2bf(v);
          else
            vtbuf[((size_t)(b * NHEADS + hh) * 64 + dd) * NTOK + n] =
                f2bf(v + biasv[cc]);
        } else {
          Cout[(size_t)grow * CDIM + gcol] = v + bias0[gcol];
        }
      }
    }
  }
}

// ---------------- flash attention v11: 2q x 2khalf blocks, LDS-staged KV ----------
// 600 blocks (= 24 bh x 25 q-pairs, bijective XCD swizzle 8x75), 4 waves each:
// hf = wv>>1 (k-half: tiles 0..24 / 25..48), wq = wv&1 (q-tile blk*2+wq).
// Each half double-buffer-stages its own K/V stream (4 global_load_lds per wave
// per tile); halves are independent between barriers -> 2.34 waves/SIMD of
// independent ~700cy chains (R10 had 1.15 -> chain-latency-bound at 746cy/tile).
// V LDS now XOR-swizzled (chunk ^= (d>>1)&3, staged via pre-swizzled source,
// rule #21): 16-way -> 4-way bank conflicts. End: two-phase LDS merge per pair.
__global__ __launch_bounds__(256) void attn_kernel(
    const unsigned short* __restrict__ qbuf,
    const unsigned short* __restrict__ kbuf,
    const unsigned short* __restrict__ vtbuf,
    const unsigned short* __restrict__ bias1Q,
    const float* __restrict__ bias2,
    unsigned short* __restrict__ aout) {
  __shared__ __align__(16) char smem[32768];
  unsigned short* stg = (unsigned short*)smem;  // [hf][K dbuf 2x2048 | V dbuf 2x2048]
  float* mb = (float*)smem;                     // merge: [2][64][19] f32 (9.7KB)

  const int lane = threadIdx.x & 63;
  const int wv = threadIdx.x >> 6;   // 0..3
  const int hf = wv >> 1;            // k-half
  const int wq = wv & 1;             // q-tile within pair
  const int wu = (blockIdx.x & 7) * 75 + (blockIdx.x >> 3);  // 0..599
  const int bh = wu / 25;
  const int blk = wu - bh * 25;
  const int qt = blk * 2 + wq;       // 0..50; 49,50 inactive
  const bool active = qt < 49;
  const int q0 = active ? qt * 32 : 0;
  const int h = bh % NHEADS;
  const int b = bh / NHEADS;
  const int qlane = lane & 31;
  const int hi = lane >> 5;
  const int hi4 = hi * 4;
  const int qn = q0 + qlane;
  const int qfr = qn / TPF < 7 ? qn / TPF : 7;
  const int qmod = qn % AREA1;

  const int ntile = 25 - hf;         // 25 (tiles 0..24) or 24 (tiles 25..48)
  const int kstart = hf * 800;       // first k index of this half

  const unsigned short* qp = qbuf + (size_t)bh * NTOK * DHEAD;
  const unsigned short* kp = kbuf + (size_t)bh * NTOK * DHEAD;
  const unsigned short* vp = vtbuf + (size_t)bh * DHEAD * NTOK;
  const unsigned short* bq = bias1Q + ((size_t)h * AREA1 + qmod) * EXT1 + hi4;
  const float* b2q = bias2 + h * 64 + qfr * 8;

  unsigned short* Ks = stg + hf * 8192;         // [2][2048] elems
  unsigned short* Vs = stg + hf * 8192 + 4096;  // [2][2048] elems

  // staging source lanes (pre-swizzled): wave wq handles K instrs i=wq*2,wq*2+1
  // (rows i*8+(l>>3), phys slot l&7 holds logical d-chunk (l&7)^(l>>3)) and
  // V instrs j=wq*2,wq*2+1 (d-rows j*16+(l>>2), phys slot l&3 holds logical
  // k-chunk (l&3)^((l>>3)&3)).
  const unsigned short* kst0 = kp + (size_t)(kstart + wq * 16 + (lane >> 3)) * DHEAD +
                               (((lane & 7) ^ (lane >> 3)) << 3);
  const unsigned short* kst1 = kst0 + (size_t)8 * DHEAD;
  const unsigned short* vst0 = vp + (size_t)(wq * 32 + (lane >> 2)) * NTOK + kstart +
                               (((lane & 3) ^ ((lane >> 3) & 3)) << 3);
  const unsigned short* vst1 = vst0 + (size_t)16 * NTOK;

  auto stage = [&](int buf, int dt) {
    __builtin_amdgcn_global_load_lds(
        (const __attribute__((address_space(1))) void*)(kst0 + (size_t)dt * 32 * DHEAD),
        (__attribute__((address_space(3))) void*)&Ks[buf * 2048 + wq * 1024], 16, 0, 0);
    __builtin_amdgcn_global_load_lds(
        (const __attribute__((address_space(1))) void*)(kst1 + (size_t)dt * 32 * DHEAD),
        (__attribute__((address_space(3))) void*)&Ks[buf * 2048 + wq * 1024 + 512], 16, 0, 0);
    __builtin_amdgcn_global_load_lds(
        (const __attribute__((address_space(1))) void*)(vst0 + dt * 32),
        (__attribute__((address_space(3))) void*)&Vs[buf * 2048 + wq * 1024], 16, 0, 0);
    __builtin_amdgcn_global_load_lds(
        (const __attribute__((address_space(1))) void*)(vst1 + dt * 32),
        (__attribute__((address_space(3))) void*)&Vs[buf * 2048 + wq * 1024 + 512], 16, 0, 0);
  };

  bf16x8 aq[4];
#pragma unroll
  for (int c = 0; c < 4; ++c)
    aq[c] = ld8(qp + (size_t)qn * DHEAD + c * 16 + hi * 8);

  f32x16 o0 = {}, o1 = {};
  float mrun = -1.0e30f, lrun = 0.f;

  stage(0, 0);
  unsigned short ub[16];
  int base = kstart % AREA1;                  // 0 or 12
  int kfl = kstart / TPF;                     // 0 or 4
  int ccr = (kfl + 1) * TPF - kstart;         // 196 or 180
  {
    const unsigned short* bp = bq + base;
#pragma unroll
    for (int r = 0; r < 16; ++r) ub[r] = bp[(r & 3) + 8 * (r >> 2)];
  }
  float b2lo = b2q[kfl], b2hi = b2q[kfl < 7 ? kfl + 1 : 7];
  const int vswz = (qlane >> 1) & 3;          // V read swizzle key
  __syncthreads();

  int cur = 0;
  for (int t = 0; t < 25; ++t) {
    if (t + 1 < ntile) stage(cur ^ 1, t + 1);
    if (t < ntile) {
      const int kv0 = kstart + t * 32;
      bf16x8 kf[4], vf[4];
#pragma unroll
      for (int c = 0; c < 4; ++c)
        kf[c] = ld8(&Ks[cur * 2048 + qlane * 64 + ((((c << 1) + hi) ^ (qlane & 7)) << 3)]);
      vf[0] = ld8(&Vs[cur * 2048 + qlane * 32 + ((hi ^ vswz) << 3)]);
      vf[1] = ld8(&Vs[cur * 2048 + qlane * 32 + (((2 + hi) ^ vswz) << 3)]);
      vf[2] = ld8(&Vs[cur * 2048 + (32 + qlane) * 32 + ((hi ^ vswz) << 3)]);
      vf[3] = ld8(&Vs[cur * 2048 + (32 + qlane) * 32 + (((2 + hi) ^ vswz) << 3)]);

      f32x16 s;
#pragma unroll
      for (int r = 0; r < 16; ++r) s[r] = bf2f(ub[r]);
      __builtin_amdgcn_s_setprio(1);
#pragma unroll
      for (int c = 0; c < 4; ++c) s = mfma32(kf[c], aq[c], s);
      __builtin_amdgcn_s_setprio(0);

      // prefetch next tile's bias1 chunk
      int basen = base + 32; if (basen >= AREA1) basen -= AREA1;
      if (t + 1 < ntile) {
        const unsigned short* bp = bq + basen;
#pragma unroll
        for (int r = 0; r < 16; ++r) ub[r] = bp[(r & 3) + 8 * (r >> 2)];
      }

      if (ccr < 32) {  // frame-boundary crossing tile
        const float dlt = b2hi - b2lo;
#pragma unroll
        for (int r = 0; r < 16; ++r)
          s[r] += ((r & 3) + 8 * (r >> 2) + hi4 >= ccr) ? dlt : 0.f;
      }

      float a0 = fmaxf(fmaxf(s[0], s[1]), s[2]);
      float a1 = fmaxf(fmaxf(s[3], s[4]), s[5]);
      float a2 = fmaxf(fmaxf(s[6], s[7]), s[8]);
      float a3 = fmaxf(fmaxf(s[9], s[10]), s[11]);
      float a4 = fmaxf(fmaxf(s[12], s[13]), s[14]);
      float tmax = fmaxf(fmaxf(fmaxf(a0, a1), a2), fmaxf(fmaxf(a3, a4), s[15]));
      {
        unsigned int tx, ty;
        swap32(__builtin_bit_cast(unsigned int, tmax),
               __builtin_bit_cast(unsigned int, tmax), tx, ty);
        tmax = fmaxf(__builtin_bit_cast(float, tx), __builtin_bit_cast(float, ty));
      }
      const float tb = tmax + b2lo;
      if (!__all(tb - mrun <= 11.5f)) {  // T13 defer-max (log2 domain)
        const float mnew = fmaxf(mrun, tb);
        const float fac = EXP2(mrun - mnew);
        lrun *= fac;
#pragma unroll
        for (int r = 0; r < 16; ++r) { o0[r] *= fac; o1[r] *= fac; }
        mrun = mnew;
      }
      const float mm = mrun - b2lo;
#pragma unroll
      for (int r = 0; r < 16; ++r) s[r] = EXP2(s[r] - mm);
      float s0a = (s[0] + s[1]) + (s[2] + s[3]);
      float s1a = (s[4] + s[5]) + (s[6] + s[7]);
      float s2a = (s[8] + s[9]) + (s[10] + s[11]);
      float s3a = (s[12] + s[13]) + (s[14] + s[15]);
      float ps = (s0a + s1a) + (s2a + s3a);
      {
        unsigned int px, py;
        swap32(__builtin_bit_cast(unsigned int, ps),
               __builtin_bit_cast(unsigned int, ps), px, py);
        ps = __builtin_bit_cast(float, px) + __builtin_bit_cast(float, py);
      }
      lrun += ps;

      unsigned int dw[8];
#pragma unroll
      for (int c = 0; c < 8; ++c) dw[c] = pack2(s[2 * c], s[2 * c + 1]);
      unsigned int f0[4], f1[4];
      swap32(dw[0], dw[2], f0[0], f0[2]);
      swap32(dw[1], dw[3], f0[1], f0[3]);
      swap32(dw[4], dw[6], f1[0], f1[2]);
      swap32(dw[5], dw[7], f1[1], f1[3]);
      const bf16x8 F0 = __builtin_bit_cast(bf16x8, *(ulonglong2*)f0);
      const bf16x8 F1 = __builtin_bit_cast(bf16x8, *(ulonglong2*)f1);

      __builtin_amdgcn_s_setprio(1);
      o0 = mfma32(vf[0], F0, o0);
      o0 = mfma32(vf[1], F1, o0);
      o1 = mfma32(vf[2], F0, o1);
      o1 = mfma32(vf[3], F1, o1);
      __builtin_amdgcn_s_setprio(0);

      base = basen;
      ccr -= 32;
      if (ccr <= 0) {
        kfl++;
        ccr += TPF;
        b2lo = b2q[kfl];
        b2hi = b2q[kfl < 7 ? kfl + 1 : 7];
      }
    }
    __syncthreads();
    cur ^= 1;
  }

  // ---- merge halves: pair (hf0,wq) <- (hf1,wq); two-phase via reused smem ----
  float* row = mb + ((size_t)(wq * 64 + lane)) * 19;
  if (hf == 1) {
#pragma unroll
    for (int r = 0; r < 16; ++r) row[r] = o0[r];
    row[16] = mrun;
    row[17] = lrun;
  }
  __syncthreads();
  float w0 = 1.f, w1 = 0.f, rinv = 1.f;
  unsigned short* op = aout + (size_t)(b * NTOK + qn) * CDIM + h * 64;
  if (hf == 0) {
    const float m1 = row[16], l1 = row[17];
    const float M = fmaxf(mrun, m1);
    w0 = EXP2(mrun - M);
    w1 = EXP2(m1 - M);
    const float L = lrun * w0 + l1 * w1;
    rinv = 1.0f / L;
    if (active) {
#pragma unroll
      for (int c = 0; c < 8; ++c) {
        const int d0 = 8 * (c >> 1) + 4 * hi + 2 * (c & 1);
        const float v0 = (o0[2 * c] * w0 + row[2 * c] * w1) * rinv;
        const float v1 = (o0[2 * c + 1] * w0 + row[2 * c + 1] * w1) * rinv;
        *(unsigned int*)(op + d0) = pack2(v0, v1);
      }
    }
  }
  __syncthreads();
  if (hf == 1) {
#pragma unroll
    for (int r = 0; r < 16; ++r) row[r] = o1[r];
  }
  __syncthreads();
  if (hf == 0 && active) {
#pragma unroll
    for (int c = 0; c < 8; ++c) {
      const int d0 = 8 * (c >> 1) + 4 * hi + 2 * (c & 1);
      const float v0 = (o1[2 * c] * w0 + row[2 * c] * w1) * rinv;
      const float v1 = (o1[2 * c + 1] * w0 + row[2 * c + 1] * w1) * rinv;
      *(unsigned int*)(op + 32 + d0) = pack2(v0, v1);
    }
  }
}

extern "C" void kernel_launch(void* const* d_in, const int* in_sizes, int n_in,
                              void* d_out, int out_size, void* d_ws, size_t ws_size,
                              hipStream_t stream) {
  (void)in_sizes; (void)n_in; (void)out_size; (void)ws_size;
  const float* x        = (const float*)d_in[0];
  const float* qkv_w    = (const float*)d_in[1];
  const float* q_bias   = (const float*)d_in[2];
  const float* v_bias   = (const float*)d_in[3];
  const float* rp_table = (const float*)d_in[4];
  const float* rt_table = (const float*)d_in[5];
  const float* proj_w   = (const float*)d_in[6];
  const float* proj_b   = (const float*)d_in[7];
  const int* rp_index   = (const int*)d_in[8];
  const int* rt_index   = (const int*)d_in[9];

  char* ws = (char*)d_ws;
  unsigned short* xb     = (unsigned short*)(ws);
  unsigned short* qkvwb  = (unsigned short*)(ws + 4915200);
  unsigned short* projwb = (unsigned short*)(ws + 8454144);
  unsigned short* qbuf   = (unsigned short*)(ws + 9633792);
  unsigned short* kbuf   = (unsigned short*)(ws + 14450688);
  unsigned short* vtbuf  = (unsigned short*)(ws + 19267584);
  unsigned short* aout   = (unsigned short*)(ws + 24084480);
  unsigned short* bias1Q = (unsigned short*)(ws + 28999680);  // 12*197*228*2 B
  float* bias2           = (float*)(ws + 30247424);

  conv_kernel<<<2048, 256, 0, stream>>>(x, qkv_w, proj_w, xb, qkvwb, projwb, aout);
  bias_kernel<<<(NHEADS * AREA1 * EXT1 + NHEADS * 64 + 255) / 256, 256, 0, stream>>>(
      rp_table, rt_table, rp_index, rt_index, bias1Q, bias2);
  gemm_kernel<0, 128, 64><<<dim3(K3 / 64, MPAD / 128), 256, 0, stream>>>(
      xb, qkvwb, q_bias, v_bias, qbuf, kbuf, vtbuf, nullptr);
  attn_kernel<<<dim3(600), 256, 0, stream>>>(
      qbuf, kbuf, vtbuf, bias1Q, bias2, aout);
  gemm_kernel<1, 64, 64><<<dim3(CDIM / 64, MPAD / 64), 256, 0, stream>>>(
      aout, projwb, proj_b, nullptr, nullptr, nullptr, nullptr, (float*)d_out);
}